// Round 10
// baseline (730.633 us; speedup 1.0000x reference)
//
#include <hip/hip_runtime.h>
#include <math.h>

#define B_   64
#define TOK_ 64
#define NT_  456
#define L_   457
#define D_   256
#define H_   8
#define HD_  32
#define FF_  1024
#define NL_  4
#define PH_  32
#define MPAD 29440   // 115 * 256 (rows padded for 256-row GEMM tiles; = 920*32)

typedef unsigned int uint;
typedef unsigned short ushort;
typedef __bf16 v8bf __attribute__((ext_vector_type(8)));
typedef __bf16 v4bf __attribute__((ext_vector_type(4)));
typedef short v4s __attribute__((ext_vector_type(4)));
typedef float v4f __attribute__((ext_vector_type(4)));

__device__ __forceinline__ float bu2f(ushort x) {
    return __uint_as_float(((uint)x) << 16);
}
__device__ __forceinline__ ushort f2bu(float f) {
    union { float f; uint u; } x; x.f = f;
    uint r = (x.u + 0x7fffu + ((x.u >> 16) & 1u)) >> 16;
    return (ushort)r;
}
__device__ __forceinline__ uint pack_bf2(float a, float b) {
#if defined(__HIP_DEVICE_COMPILE__) && __has_builtin(__builtin_amdgcn_cvt_pk_bf16_f32)
    typedef __bf16 bf2v __attribute__((ext_vector_type(2)));
    bf2v v = __builtin_amdgcn_cvt_pk_bf16_f32(a, b);
    return *(uint*)&v;
#else
    return (uint)f2bu(a) | ((uint)f2bu(b) << 16);
#endif
}

// K=16 bf16 MFMA (PV with register-resident P). Guarded for the host pass.
__device__ __forceinline__ v4f mfma16(uint2 a, uint2 b, v4f c) {
#if defined(__HIP_DEVICE_COMPILE__)
#if __has_builtin(__builtin_amdgcn_mfma_f32_16x16x16_bf16)
    return __builtin_amdgcn_mfma_f32_16x16x16_bf16(*(v4bf*)&a, *(v4bf*)&b, c, 0, 0, 0);
#else
    return __builtin_amdgcn_mfma_f32_16x16x16bf16_1k(*(v4s*)&a, *(v4s*)&b, c, 0, 0, 0);
#endif
#else
    (void)a; (void)b;
    return c;
#endif
}

// async global->LDS 16B copy; lds base wave-uniform, data at base + lane*16.
__device__ __forceinline__ void gload16(const void* g, void* l) {
    __builtin_amdgcn_global_load_lds(
        (const __attribute__((address_space(1))) void*)(unsigned long long)(uintptr_t)g,
        (__attribute__((address_space(3))) void*)(uint)(uintptr_t)l,
        16, 0, 0);
}

// ---------------------------------------------------------------------------
// Pipelined bf16 MFMA GEMM (T3+T4+T5): C[M,N] = A[M,K]·W^T[N,K] + bias.
// 256x128 tile, 8 waves (4x2), BK=32, ring-3 LDS buffer. Steady-state wait is
// s_waitcnt vmcnt(3); vmcnt(0) only at the last tile. setprio around MFMAs.
// ---------------------------------------------------------------------------
__global__ __launch_bounds__(512, 2) void mfma_gemm8(
    const ushort* __restrict__ A, const ushort* __restrict__ WT,
    const float* __restrict__ bias, ushort* __restrict__ Cout,
    int N, int K, int relu)
{
    __shared__ ushort lds[36864];   // 72 KB: A-ring 3x8192, B-ring 3x4096

    const int NK = K >> 5;

    // bijective XCD-aware remap (works for any grid size)
    int nwg = gridDim.x, orig = blockIdx.x;
    int qd = nwg >> 3, rd = nwg & 7;
    int xcd = orig & 7, wi = orig >> 3;
    int wgid = (xcd < rd ? xcd * (qd + 1) : rd * (qd + 1) + (xcd - rd) * qd) + wi;
    int nCB = N >> 7;
    int colblk = (wgid % nCB) << 7;
    int rowblk = (wgid / nCB) << 8;

    int tid = threadIdx.x;
    int wave = tid >> 6, lane = tid & 63;
    int wm = wave >> 1, wn = wave & 1;     // 4x2 wave grid: 64 rows x 64 cols each
    int fr = lane & 15, fq = lane >> 4;

    // ---- staging source pointers (pre-swizzled global addresses) ----
    const ushort* srcA0; const ushort* srcA1; const ushort* srcB0;
    {
        int idx = tid;
        int c = idx >> 3, G = (idx & 7) ^ (c & 7);
        srcA0 = A + (size_t)(rowblk + c * 2 + (G >> 2)) * K + (G & 3) * 8;
        idx = 512 + tid;
        c = idx >> 3; G = (idx & 7) ^ (c & 7);
        srcA1 = A + (size_t)(rowblk + c * 2 + (G >> 2)) * K + (G & 3) * 8;
        idx = tid;
        c = idx >> 3; G = (idx & 7) ^ (c & 7);
        srcB0 = WT + (size_t)(colblk + c * 2 + (G >> 2)) * K + (G & 3) * 8;
    }
    int duA0 = (wave * 64) * 8;          // ushort offsets (wave-uniform bases)
    int duA1 = (512 + wave * 64) * 8;
    int duB  = (wave * 64) * 8;

    // ---- fragment LDS offsets (ushort), swizzled to match staging ----
    int aoff[4], boff[4];
#pragma unroll
    for (int i = 0; i < 4; ++i) {
        int rl = wm * 64 + i * 16 + fr;
        int c = rl >> 1;
        aoff[i] = c * 64 + ((((rl & 1) * 4 + fq) ^ (c & 7)) * 8);
        rl = wn * 64 + i * 16 + fr;
        c = rl >> 1;
        boff[i] = c * 64 + ((((rl & 1) * 4 + fq) ^ (c & 7)) * 8);
    }

    v4f acc[4][4];
#pragma unroll
    for (int i = 0; i < 4; ++i)
#pragma unroll
        for (int j = 0; j < 4; ++j) acc[i][j] = (v4f)0.0f;

    // ---- prologue: stage tiles 0,1 into slots 0,1 (6 loads in flight) ----
#pragma unroll
    for (int t = 0; t < 2; ++t) {
        ushort* pa = lds + t * 8192;
        ushort* pb = lds + 24576 + t * 4096;
        gload16(srcA0 + t * 32, pa + duA0);
        gload16(srcA1 + t * 32, pa + duA1);
        gload16(srcB0 + t * 32, pb + duB);
    }

    // ---- main loop: one barrier period per BK=32 tile ----
    for (int t = 0; t < NK; ++t) {
        int slot = t % 3, pslot = (t + 2) % 3;
        const ushort* As = lds + slot * 8192;
        const ushort* Bs = lds + 24576 + slot * 4096;

        if (t < NK - 1) asm volatile("s_waitcnt vmcnt(3)" ::: "memory");
        else            asm volatile("s_waitcnt vmcnt(0)" ::: "memory");
        __builtin_amdgcn_s_barrier();
        asm volatile("" ::: "memory");

        if (t + 2 < NK) {   // stage tile t+2 into the slot freed by t-1
            ushort* pa = lds + pslot * 8192;
            ushort* pb = lds + 24576 + pslot * 4096;
            gload16(srcA0 + (t + 2) * 32, pa + duA0);
            gload16(srcA1 + (t + 2) * 32, pa + duA1);
            gload16(srcB0 + (t + 2) * 32, pb + duB);
        }

        v8bf av[4], bw[4];
#pragma unroll
        for (int i = 0; i < 4; ++i) av[i] = *(const v8bf*)(As + aoff[i]);
#pragma unroll
        for (int i = 0; i < 4; ++i) bw[i] = *(const v8bf*)(Bs + boff[i]);

        __builtin_amdgcn_s_setprio(1);
#pragma unroll
        for (int mi = 0; mi < 4; ++mi)
#pragma unroll
            for (int ni = 0; ni < 4; ++ni)
                acc[mi][ni] = __builtin_amdgcn_mfma_f32_16x16x32_bf16(
                    av[mi], bw[ni], acc[mi][ni], 0, 0, 0);
        __builtin_amdgcn_s_setprio(0);
    }

    // ---- epilogue: acc -> LDS (pitch 136) -> coalesced uint4 stores ----
    __syncthreads();
    {
        const int PIT = 136;
#pragma unroll
        for (int ni = 0; ni < 4; ++ni) {
            int col = wn * 64 + ni * 16 + fr;
            float bv = bias[colblk + col];
#pragma unroll
            for (int mi = 0; mi < 4; ++mi) {
                int row0 = wm * 64 + mi * 16 + fq * 4;
#pragma unroll
                for (int r2 = 0; r2 < 4; ++r2) {
                    float v = acc[mi][ni][r2] + bv;
                    if (relu) v = fmaxf(v, 0.f);
                    lds[(row0 + r2) * PIT + col] = f2bu(v);
                }
            }
        }
        __syncthreads();
#pragma unroll
        for (int i = 0; i < 8; ++i) {
            int u = tid + 512 * i;            // 0..4095 uint4 of the 256x128 tile
            int row = u >> 4, c8 = (u & 15) * 8;
            uint4 val = *(const uint4*)&lds[row * PIT + c8];
            *(uint4*)(Cout + (size_t)(rowblk + row) * N + colblk + c8) = val;
        }
    }
}

// ---------------------------------------------------------------------------
// Fused block tail v6: Xb <- LN2( LN1(Xb+AO) + FFN(LN1(Xb+AO)) ), 32 rows/blk.
// R9 post-mortem: occupancy was GRID-limited (460 blocks / 256 CUs = 1.8/CU),
// not LDS-limited -- shrinking LDS couldn't help. Fix: 32-row blocks -> 920
// blocks = 3.6/CU; LDS 24.3 KB (Xs 16 KB + Hs 8.25 KB) -> wave-limited at
// 4 blocks/CU (32 waves). Same swizzle formulas as the R9-verified kernel
// (row-local; k-tile now 1024 ushorts, chunk c in 0..15). u register-resident
// (ur[4]); epilogue C split Hs(132)/Xs(136). Weights re-read 2x from L2
// (~+7us at 34.5 TB/s) -- cheap vs doubling TLP on an all-pipes-idle kernel.
// ---------------------------------------------------------------------------
__global__ __launch_bounds__(512, 4) void ffn_kernel(
    const ushort* __restrict__ Xres, const ushort* __restrict__ AO,
    const float* __restrict__ l1g, const float* __restrict__ l1b,
    const ushort* __restrict__ W1P, const ushort* __restrict__ W2P,
    const float* __restrict__ b1, const float* __restrict__ b2,
    const float* __restrict__ l2g, const float* __restrict__ l2b,
    ushort* __restrict__ Xout)
{
    __shared__ ushort Xs[8192];       // u (FF1 A), later C cols 128..255 (pitch 136)
    __shared__ ushort Hs[32 * 132];   // H eighth 32r x 128c; later C cols 0..127

    int r0 = blockIdx.x * 32;
    int tid = threadIdx.x;
    int wave = tid >> 6, lane = tid & 63;
    int fr = lane & 15, fq = lane >> 4;

    // ---- prologue: u = LN1(Xres + AO) -> ur[] regs + Xs (FF1-swizzled) ----
    uint2 ur[4];
    {
        float4 g1 = *(const float4*)(l1g + lane * 4);
        float4 be1 = *(const float4*)(l1b + lane * 4);
        ushort4 xr[4], ar[4];
#pragma unroll
        for (int rr = 0; rr < 4; ++rr) {
            size_t off = (size_t)(r0 + wave * 4 + rr) * 256 + lane * 4;
            xr[rr] = *(const ushort4*)(Xres + off);
            ar[rr] = *(const ushort4*)(AO + off);
        }
#pragma unroll
        for (int rr = 0; rr < 4; ++rr) {
            int row = wave * 4 + rr;
            float4 v;
            v.x = bu2f(xr[rr].x) + bu2f(ar[rr].x);
            v.y = bu2f(xr[rr].y) + bu2f(ar[rr].y);
            v.z = bu2f(xr[rr].z) + bu2f(ar[rr].z);
            v.w = bu2f(xr[rr].w) + bu2f(ar[rr].w);
            float s = v.x + v.y + v.z + v.w;
#pragma unroll
            for (int o = 1; o < 64; o <<= 1) s += __shfl_xor(s, o);
            float mean = s * (1.0f / 256.0f);
            float4 d;
            d.x = v.x - mean; d.y = v.y - mean; d.z = v.z - mean; d.w = v.w - mean;
            float sq = d.x * d.x + d.y * d.y + d.z * d.z + d.w * d.w;
#pragma unroll
            for (int o = 1; o < 64; o <<= 1) sq += __shfl_xor(sq, o);
            float rstd = rsqrtf(sq * (1.0f / 256.0f) + 1e-5f);
            ushort4 hb;
            hb.x = f2bu(d.x * rstd * g1.x + be1.x);
            hb.y = f2bu(d.y * rstd * g1.y + be1.y);
            hb.z = f2bu(d.z * rstd * g1.z + be1.z);
            hb.w = f2bu(d.w * rstd * g1.w + be1.w);
            ur[rr] = *(uint2*)&hb;
            // swizzled Xs address for (row, cols lane*4..lane*4+3)
            int kt = lane >> 3, g = (lane >> 1) & 3, c = row >> 1;
            int Gp = ((row & 1) * 4 + g) ^ (c & 7);
            int addr = kt * 1024 + (c * 8 + Gp) * 8 + (lane & 1) * 4;
            *(uint2*)&Xs[addr] = ur[rr];
        }
    }

    // A-frag offsets within a k-tile (FF1; rows 0..31)
    int aoffs[2];
#pragma unroll
    for (int mi = 0; mi < 2; ++mi) {
        int ar2 = mi * 16 + fr, c = ar2 >> 1;
        aoffs[mi] = c * 64 + ((((ar2 & 1) * 4 + fq) ^ (c & 7)) * 8);
    }
    int wm2 = wave >> 2, wn2 = wave & 3;   // FF2 wave grid 2x4 (16 rows x 64 cols)

    v4f acc2[4];
#pragma unroll
    for (int j = 0; j < 4; ++j) acc2[j] = (v4f)0.0f;

    __syncthreads();

#pragma unroll
    for (int e = 0; e < 8; ++e) {
        // ---- FF1: this wave's 16 H-cols of eighth e ----
        v4f acc1[2];
#pragma unroll
        for (int i = 0; i < 2; ++i) acc1[i] = (v4f)0.0f;

        const ushort* w1p = W1P + ((size_t)(e * 8 + wave) * 8) * 512;
#pragma unroll
        for (int kc = 0; kc < 8; ++kc) {
            v8bf bf0 = *(const v8bf*)(w1p + (size_t)kc * 512 + lane * 8);
#pragma unroll
            for (int mi = 0; mi < 2; ++mi) {
                v8bf a = *(const v8bf*)(Xs + kc * 1024 + aoffs[mi]);
                acc1[mi] = __builtin_amdgcn_mfma_f32_16x16x32_bf16(
                    a, bf0, acc1[mi], 0, 0, 0);
            }
        }
        float b1v = b1[e * 128 + wave * 16 + fr];

        if (e) __syncthreads();            // prev eighth's FF2 reads done
        // ---- relu + bias, write H eighth (col_local = wave*16+fr) ----
#pragma unroll
        for (int mi = 0; mi < 2; ++mi) {
            int row0 = mi * 16 + fq * 4;
#pragma unroll
            for (int r2 = 0; r2 < 4; ++r2)
                Hs[(row0 + r2) * 132 + wave * 16 + fr] =
                    f2bu(fmaxf(acc1[mi][r2] + b1v, 0.f));
        }
        __syncthreads();

        // ---- FF2 partial: acc2 += H_e @ W2^T[:, e*128 .. +128) ----
#pragma unroll
        for (int kk = 0; kk < 4; ++kk) {
            v8bf bw2[4];
#pragma unroll
            for (int ni = 0; ni < 4; ++ni)
                bw2[ni] = *(const v8bf*)(W2P +
                    ((size_t)(((wn2 * 4 + ni) * 32 + e * 4 + kk)) * 512) + lane * 8);
            v8bf a2 = *(const v8bf*)(Hs +
                (wm2 * 16 + fr) * 132 + kk * 32 + fq * 8);
#pragma unroll
            for (int ni = 0; ni < 4; ++ni)
                acc2[ni] = __builtin_amdgcn_mfma_f32_16x16x32_bf16(
                    a2, bw2[ni], acc2[ni], 0, 0, 0);
        }
    }

    // ---- epilogue: C = acc2+b2 staged split (Hs: cols 0..127, Xs: 128..255);
    //      then Xb = LN2(u + C) with u from ur[] registers ----
    __syncthreads();
    {
        float b2v[4];
#pragma unroll
        for (int ni = 0; ni < 4; ++ni) b2v[ni] = b2[wn2 * 64 + ni * 16 + fr];
#pragma unroll
        for (int ni = 0; ni < 4; ++ni) {
            int col = wn2 * 64 + ni * 16 + fr;
            int row0 = wm2 * 16 + fq * 4;
#pragma unroll
            for (int r2 = 0; r2 < 4; ++r2) {
                ushort cvb = f2bu(acc2[ni][r2] + b2v[ni]);
                if (wn2 < 2) Hs[(row0 + r2) * 132 + col] = cvb;
                else         Xs[(row0 + r2) * 136 + col - 128] = cvb;
            }
        }
        __syncthreads();

        float4 g2 = *(const float4*)(l2g + lane * 4);
        float4 be2 = *(const float4*)(l2b + lane * 4);
#pragma unroll
        for (int rr = 0; rr < 4; ++rr) {
            int row = wave * 4 + rr;
            ushort4 cv;
            if (lane < 32) cv = *(const ushort4*)&Hs[row * 132 + lane * 4];
            else           cv = *(const ushort4*)&Xs[row * 136 + lane * 4 - 128];
            ushort4 uv = *(ushort4*)&ur[rr];
            float4 v;
            v.x = bu2f(cv.x) + bu2f(uv.x);
            v.y = bu2f(cv.y) + bu2f(uv.y);
            v.z = bu2f(cv.z) + bu2f(uv.z);
            v.w = bu2f(cv.w) + bu2f(uv.w);
            float s = v.x + v.y + v.z + v.w;
#pragma unroll
            for (int o = 1; o < 64; o <<= 1) s += __shfl_xor(s, o);
            float mean = s * (1.0f / 256.0f);
            float4 d;
            d.x = v.x - mean; d.y = v.y - mean; d.z = v.z - mean; d.w = v.w - mean;
            float sq = d.x * d.x + d.y * d.y + d.z * d.z + d.w * d.w;
#pragma unroll
            for (int o = 1; o < 64; o <<= 1) sq += __shfl_xor(sq, o);
            float rstd = rsqrtf(sq * (1.0f / 256.0f) + 1e-5f);
            ushort4 hb;
            hb.x = f2bu(d.x * rstd * g2.x + be2.x);
            hb.y = f2bu(d.y * rstd * g2.y + be2.y);
            hb.z = f2bu(d.z * rstd * g2.z + be2.z);
            hb.w = f2bu(d.w * rstd * g2.w + be2.w);
            *(ushort4*)(Xout + (size_t)(r0 + row) * 256 + lane * 4) = hb;
        }
    }
}

// ---------------------------------------------------------------------------
// Pack fp32 W[K][N] (one layer per blockIdx.z) into MFMA B-frag order:
// P[((grp*(K/32)+kc)*64+lane)*8+e] = bf16(W[(kc*32+(lane>>4)*8+e)*N + grp*16+(lane&15)])
// ---------------------------------------------------------------------------
__global__ __launch_bounds__(256) void wpack_kernel(
    const float* __restrict__ W, ushort* __restrict__ P, int K, int N)
{
    int KC = K >> 5;
    int total = (N >> 4) * KC * 64;
    const float* Wl = W + (size_t)blockIdx.z * K * N;
    ushort* Pl = P + (size_t)blockIdx.z * K * N;
    int gid = blockIdx.x * 256 + threadIdx.x;
    if (gid >= total) return;
    int lane = gid & 63;
    int t = gid >> 6;
    int kc = t % KC, grp = t / KC;
    int n = grp * 16 + (lane & 15);
    int k0 = kc * 32 + (lane >> 4) * 8;
    float v[8];
#pragma unroll
    for (int e = 0; e < 8; ++e) v[e] = Wl[(size_t)(k0 + e) * N + n];
    uint4 o;
    o.x = pack_bf2(v[0], v[1]);
    o.y = pack_bf2(v[2], v[3]);
    o.z = pack_bf2(v[4], v[5]);
    o.w = pack_bf2(v[6], v[7]);
    *(uint4*)&Pl[(size_t)gid * 8] = o;
}

// ---------------------------------------------------------------------------
__global__ __launch_bounds__(256) void wcast_kernel(
    const float* __restrict__ W, ushort* __restrict__ WT, int K, int N)
{
    __shared__ float t[32][33];
    const float* Wl = W + (size_t)blockIdx.z * K * N;
    ushort* WTl = WT + (size_t)blockIdx.z * K * N;
    int n0 = blockIdx.x * 32, k0 = blockIdx.y * 32;
    int tx = threadIdx.x, ty = threadIdx.y;
#pragma unroll
    for (int r = 0; r < 32; r += 8)
        t[ty + r][tx] = Wl[(size_t)(k0 + ty + r) * N + n0 + tx];
    __syncthreads();
#pragma unroll
    for (int r = 0; r < 32; r += 8)
        WTl[(size_t)(n0 + ty + r) * K + k0 + tx] = f2bu(t[tx][ty + r]);
}

// ---------------------------------------------------------------------------
// fp32 SGEMM for the embed GEMM only; row-remap; writes bf16 Xb only.
// ---------------------------------------------------------------------------
__global__ __launch_bounds__(256) void sgemm_kernel(
    const float* __restrict__ A, const float* __restrict__ W,
    const float* __restrict__ bias, ushort* __restrict__ Cb,
    int M, int N, int K)
{
    __shared__ float As_[16][64];
    __shared__ float Bs_[16][64];
    int tid = threadIdx.x;
    int rowblk = blockIdx.y * 64;
    int colblk = blockIdx.x * 64;
    int a_row = tid & 63, a_q = tid >> 6;
    int b_kr = tid >> 4, b_cg = tid & 15;
    int rm = tid >> 4, cn = tid & 15;
    float acc[4][4] = {};
    const float* Aptr = A + (size_t)(rowblk + a_row) * K;
    for (int kt = 0; kt < K; kt += 16) {
        float4 av = *(const float4*)(Aptr + kt + a_q * 4);
        float4 bv = *(const float4*)(W + (size_t)(kt + b_kr) * N + colblk + b_cg * 4);
        As_[a_q * 4 + 0][a_row] = av.x;
        As_[a_q * 4 + 1][a_row] = av.y;
        As_[a_q * 4 + 2][a_row] = av.z;
        As_[a_q * 4 + 3][a_row] = av.w;
        *(float4*)&Bs_[b_kr][b_cg * 4] = bv;
        __syncthreads();
#pragma unroll
        for (int kk = 0; kk < 16; ++kk) {
            float4 a4 = *(const float4*)&As_[kk][rm * 4];
            float4 b4 = *(const float4*)&Bs_[kk][cn * 4];
            float ar[4] = {a4.x, a4.y, a4.z, a4.w};
            float br[4] = {b4.x, b4.y, b4.z, b4.w};
#pragma unroll
            for (int i = 0; i < 4; ++i)
#pragma unroll
                for (int j = 0; j < 4; ++j) acc[i][j] += ar[i] * br[j];
        }
        __syncthreads();
    }
    float4 bv = *(const float4*)(bias + colblk + cn * 4);
    float bb[4] = {bv.x, bv.y, bv.z, bv.w};
#pragma unroll
    for (int i = 0; i < 4; ++i) {
        int grow = rowblk + rm * 4 + i;
        size_t orow = (size_t)(grow + grow / NT_ + 1);
        ushort4 h;
        h.x = f2bu(acc[i][0] + bb[0]);
        h.y = f2bu(acc[i][1] + bb[1]);
        h.z = f2bu(acc[i][2] + bb[2]);
        h.w = f2bu(acc[i][3] + bb[3]);
        *(ushort4*)(Cb + orow * N + colblk + cn * 4) = h;
    }
}

__global__ __launch_bounds__(256) void cls_kernel(
    const float* __restrict__ coords, const float* __restrict__ w_cls,
    const float* __restrict__ b_cls, ushort* __restrict__ Xb)
{
    int b = blockIdx.x;
    int t = threadIdx.x;
    float c0 = coords[b * 3 + 0], c1 = coords[b * 3 + 1], c2 = coords[b * 3 + 2];
    float v = c0 * w_cls[t] + c1 * w_cls[D_ + t] + c2 * w_cls[2 * D_ + t] + b_cls[t];
    Xb[(size_t)b * L_ * D_ + t] = f2bu(v);
}

// ---------------------------------------------------------------------------
// MFMA attention v7 (banded alibi): one block per (b,h), 512 threads.
// (R1 exact version -- verified best.)
// ---------------------------------------------------------------------------
__global__ __launch_bounds__(512) void attn_kernel(
    const ushort* __restrict__ qkv, ushort* __restrict__ out)
{
    __shared__ __align__(16) ushort Ks[464][40];    // 36.3 KB
    __shared__ __align__(16) ushort Vt[32][488];    // 30.5 KB

    int h = blockIdx.x, b = blockIdx.y;
    int tid = threadIdx.x;
    int wave = tid >> 6, lane = tid & 63;
    int fr = lane & 15, fq = lane >> 4;
    const float scale2 = 0.17677669529663687f * 1.4426950408889634f;
    float slope2 = ((h < 4) ? 1.0f : 0.5f) * 1.4426950408889634f;
    int W = (h < 4) ? 32 : 64;   // band half-width (wave-uniform)
    const ushort* base = qkv + (size_t)b * L_ * 768;

    for (int j = tid >> 2; j < 464; j += 128) {
        int c8 = (tid & 3) * 8;
        uint4 u = make_uint4(0u, 0u, 0u, 0u);
        if (j < L_) u = *(const uint4*)(base + (size_t)j * 768 + 256 + h * 32 + c8);
        *(uint4*)&Ks[j][c8] = u;
    }
    for (int m = wave; m < 32; m += 8) {
        int dg = (m >> 3) * 8, jb = m & 7;
        int j = jb * 64 + lane;
        uint4 u = make_uint4(0u, 0u, 0u, 0u);
        if (j < L_) u = *(const uint4*)(base + (size_t)j * 768 + 512 + h * 32 + dg);
        if (j < 488) {
            const ushort* pu = (const ushort*)&u;
#pragma unroll
            for (int e = 0; e < 8; ++e) Vt[dg + e][j] = pu[e];
        }
    }
    __syncthreads();

    for (int pr = wave; pr < 15; pr += 8) {
        int q0 = pr * 32;
        int twoB = (pr < 14);
        int kclo = max(0, (q0 - W) >> 5);
        int kchi = min(13, (q0 + 31 + W) >> 5);      // last full 32-chunk
        int doTail = (q0 + 31 + W >= 448);
        uint4 quA = *(const uint4*)(base + (size_t)(q0 + fr) * 768 + h * 32 + fq * 8);
        v8bf qfA = *(v8bf*)&quA;
        uint4 quB = *(const uint4*)(base + (size_t)(q0 + 16 + fr) * 768 + h * 32 + fq * 8);
        v8bf qfB = *(v8bf*)&quB;
        float fqAq = (float)(q0 + fr);
        float fqBq = fqAq + 16.0f;
        float psA = 0.f, psB = 0.f;
        v4f oA0 = (v4f)0.0f, oA1 = (v4f)0.0f, oB0 = (v4f)0.0f, oB1 = (v4f)0.0f;

        for (int kc = kclo; kc <= kchi; ++kc) {
            int kb = kc * 32;
            v8bf kf0 = *(const v8bf*)&Ks[kb + fr][fq * 8];
            v8bf kf1 = *(const v8bf*)&Ks[kb + 16 + fr][fq * 8];
            uint2 va0 = *(const uint2*)&Vt[fr][kb + fq * 4];
            uint2 va1 = *(const uint2*)&Vt[16 + fr][kb + fq * 4];
            uint2 vb0 = *(const uint2*)&Vt[fr][kb + 16 + fq * 4];
            uint2 vb1 = *(const uint2*)&Vt[16 + fr][kb + 16 + fq * 4];
            float ke = (float)(kb + 4 * fq);

            v4f dA0 = (v4f)0.0f, dA1 = (v4f)0.0f;
            dA0 = __builtin_amdgcn_mfma_f32_16x16x32_bf16(kf0, qfA, dA0, 0, 0, 0);
            dA1 = __builtin_amdgcn_mfma_f32_16x16x32_bf16(kf1, qfA, dA1, 0, 0, 0);
            {
                float dl0 = fqAq - ke, dl1 = dl0 - 16.0f;
                float pe[4], po[4];
#pragma unroll
                for (int r = 0; r < 4; ++r) {
                    pe[r] = exp2f(fmaf(dA0[r], scale2, -slope2 * fabsf(dl0 - (float)r)));
                    po[r] = exp2f(fmaf(dA1[r], scale2, -slope2 * fabsf(dl1 - (float)r)));
                    psA += pe[r] + po[r];
                }
                uint2 ue, uo;
                ue.x = pack_bf2(pe[0], pe[1]); ue.y = pack_bf2(pe[2], pe[3]);
                uo.x = pack_bf2(po[0], po[1]); uo.y = pack_bf2(po[2], po[3]);
                oA0 = mfma16(va0, ue, oA0);
                oA1 = mfma16(va1, ue, oA1);
                oA0 = mfma16(vb0, uo, oA0);
                oA1 = mfma16(vb1, uo, oA1);
            }
            if (twoB) {
                v4f dB0 = (v4f)0.0f, dB1 = (v4f)0.0f;
                dB0 = __builtin_amdgcn_mfma_f32_16x16x32_bf16(kf0, qfB, dB0, 0, 0, 0);
                dB1 = __builtin_amdgcn_mfma_f32_16x16x32_bf16(kf1, qfB, dB1, 0, 0, 0);
                float dl0 = fqBq - ke, dl1 = dl0 - 16.0f;
                float pe[4], po[4];
#pragma unroll
                for (int r = 0; r < 4; ++r) {
                    pe[r] = exp2f(fmaf(dB0[r], scale2, -slope2 * fabsf(dl0 - (float)r)));
                    po[r] = exp2f(fmaf(dB1[r], scale2, -slope2 * fabsf(dl1 - (float)r)));
                    psB += pe[r] + po[r];
                }
                uint2 ue, uo;
                ue.x = pack_bf2(pe[0], pe[1]); ue.y = pack_bf2(pe[2], pe[3]);
                uo.x = pack_bf2(po[0], po[1]); uo.y = pack_bf2(po[2], po[3]);
                oB0 = mfma16(va0, ue, oB0);
                oB1 = mfma16(va1, ue, oB1);
                oB0 = mfma16(vb0, uo, oB0);
                oB1 = mfma16(vb1, uo, oB1);
            }
        }
        // tail chunk: k 448..463 (only if band reaches it)
        if (doTail) {
            v8bf kf0 = *(const v8bf*)&Ks[448 + fr][fq * 8];
            uint2 va0 = *(const uint2*)&Vt[fr][448 + fq * 4];
            uint2 va1 = *(const uint2*)&Vt[16 + fr][448 + fq * 4];
            v4f dA0 = (v4f)0.0f;
            dA0 = __builtin_amdgcn_mfma_f32_16x16x32_bf16(kf0, qfA, dA0, 0, 0, 0);
            float pe[4];
#pragma unroll
            for (int r = 0; r < 4; ++r) {
                int k = 448 + 4 * fq + r;
                pe[r] = (k < L_)
                    ? exp2f(fmaf(dA0[r], scale2, -slope2 * fabsf(fqAq - (float)k))) : 0.f;
                psA += pe[r];
            }
            uint2 ue;
            ue.x = pack_bf2(pe[0], pe[1]); ue.y = pack_bf2(pe[2], pe[3]);
            oA0 = mfma16(va0, ue, oA0);
            oA1 = mfma16(va1, ue, oA1);
            if (twoB) {
                v4f dB0 = (v4f)0.0f;
                dB0 = __builtin_amdgcn_mfma_f32_16x16x32_bf16(kf0, qfB, dB0, 0, 0, 0);
                float pf[4];
#pragma unroll
                for (int r = 0; r < 4; ++r) {
                    int k = 448 + 4 * fq + r;
                    pf[r] = (k < L_)
                        ? exp2f(fmaf(dB0[r], scale2, -slope2 * fabsf(fqBq - (float)k))) : 0.f;
                    psB += pf[r];
                }
                uint2 ub;
                ub.x = pack_bf2(pf[0], pf[1]); ub.y = pack_bf2(pf[2], pf[3]);
                oB0 = mfma16(va0, ub, oB0);
                oB1 = mfma16(va1, ub, oB1);
            }
        }

        psA += __shfl_xor(psA, 16);
        psA += __shfl_xor(psA, 32);
        psB += __shfl_xor(psB, 16);
        psB += __shfl_xor(psB, 32);
        {
            int q = q0 + fr;
            if (q < L_) {
                float inv = 1.0f / psA;
                uint2 w0, w1;
                w0.x = pack_bf2(oA0[0] * inv, oA0[1] * inv);
                w0.y = pack_bf2(oA0[2] * inv, oA0[3] * inv);
                w1.x = pack_bf2(oA1[0] * inv, oA1[1] * inv);
                w1.y = pack_bf2(oA1[2] * inv, oA1[3] * inv);
                ushort* op = out + (size_t)(b * L_ + q) * D_ + h * 32;
                *(uint2*)(op + fq * 4) = w0;
                *(uint2*)(op + 16 + fq * 4) = w1;
            }
        }
        if (twoB) {
            int q = q0 + 16 + fr;
            if (q < L_) {
                float inv = 1.0f / psB;
                uint2 w0, w1;
                w0.x = pack_bf2(oB0[0] * inv, oB0[1] * inv);
                w0.y = pack_bf2(oB0[2] * inv, oB0[3] * inv);
                w1.x = pack_bf2(oB1[0] * inv, oB1[1] * inv);
                w1.y = pack_bf2(oB1[2] * inv, oB1[3] * inv);
                ushort* op = out + (size_t)(b * L_ + q) * D_ + h * 32;
                *(uint2*)(op + fq * 4) = w0;
                *(uint2*)(op + 16 + fq * 4) = w1;
            }
        }
    }
}

// ---------------------------------------------------------------------------
// head1 via MFMA: SCp[row] = gelu(bn(Xb@th1_w + b1)) @ th2_w + b2.
// ---------------------------------------------------------------------------
__global__ __launch_bounds__(256) void head1_kernel(
    const ushort* __restrict__ Xb, const ushort* __restrict__ th1T,
    const float* __restrict__ b1, const float* __restrict__ bng,
    const float* __restrict__ bnb, const float* __restrict__ w2,
    const float* __restrict__ b2, float* __restrict__ SCp)
{
    __shared__ ushort As[128 * 32];
    __shared__ ushort Bs[32 * 264];
    int tid = threadIdx.x;
    int wave = tid >> 6, lane = tid & 63;
    int fr = lane & 15, fq = lane >> 4;
    int rowblk = blockIdx.x * 128;
    int scol = fq ^ (lane & 3) ^ ((lane >> 2) & 1);

    for (int i = tid; i < 1024; i += 256) {
        int r = i >> 5, c8 = (i & 31) * 8;
        *(uint4*)&Bs[r * 264 + c8] = *(const uint4*)(th1T + r * 256 + c8);
    }

    int c0 = wave * 64 + lane;
    int r0 = c0 >> 2, k0g = (c0 & 3) ^ (r0 & 3) ^ ((r0 >> 2) & 1);
    int c1 = 256 + c0;
    int r1 = c1 >> 2, k1g = (c1 & 3) ^ (r1 & 3) ^ ((r1 >> 2) & 1);
    const ushort* Ag0 = Xb + (size_t)(rowblk + r0) * 256 + k0g * 8;
    const ushort* Ag1 = Xb + (size_t)(rowblk + r1) * 256 + k1g * 8;
    ushort* lA0 = As + (size_t)(wave * 64) * 8;
    ushort* lA1 = As + (size_t)(256 + wave * 64) * 8;

    v4f acc[2][2];
#pragma unroll
    for (int i = 0; i < 2; ++i)
#pragma unroll
        for (int j = 0; j < 2; ++j) acc[i][j] = (v4f)0.0f;

    for (int kt = 0; kt < 256; kt += 32) {
        gload16(Ag0 + kt, lA0);
        gload16(Ag1 + kt, lA1);
        __syncthreads();
        v8bf a[2], bfr[2];
#pragma unroll
        for (int mi = 0; mi < 2; ++mi)
            a[mi] = *(const v8bf*)(As + (size_t)((wave * 2 + mi) * 16 + fr) * 32 + scol * 8);
#pragma unroll
        for (int ni = 0; ni < 2; ++ni)
            bfr[ni] = *(const v8bf*)(Bs + (size_t)(ni * 16 + fr) * 264 + kt + fq * 8);
#pragma unroll
        for (int mi = 0; mi < 2; ++mi)
#pragma unroll
            for (int ni = 0; ni < 2; ++ni)
                acc[mi][ni] = __builtin_amdgcn_mfma_f32_16x16x32_bf16(
                    a[mi], bfr[ni], acc[mi][ni], 0, 0, 0);
        __syncthreads();
    }

    const float bnr = 0.9999950000374997f;  // rsqrt(1+1e-5)
    float b1v[2], bsv[2], bbv[2], w2v[2];
#pragma unroll
    for (int ni = 0; ni < 2; ++ni) {
        int j = ni * 16 + fr;
        b1v[ni] = b1[j];
        bsv[ni] = bng[j] * bnr;
        bbv[ni] = bnb[j];
        w2v[ni] = w2[j];
    }
    const float gc = 0.7978845608028654f;
    float b2v = b2[0];
#pragma unroll
    for (int mi = 0; mi < 2; ++mi) {
#pragma unroll
        for (int r = 0; r < 4; ++r) {
            float s = 0.f;
#pragma unroll
            for (int ni = 0; ni < 2; ++ni) {
                float hb = (acc[mi][ni][r] + b1v[ni]) * bsv[ni] + bbv[ni];
                float t = tanhf(gc * (hb + 0.044715f * hb * hb * hb));
                s += 0.5f * hb * (1.0f + t) * w2v[ni];
            }
#pragma unroll
            for (int o = 1; o < 16; o <<= 1) s += __shfl_xor(s, o);
            int row = rowblk + (wave * 2 + mi) * 16 + fq * 4 + r;
            if (fr == 0 && row < B_ * L_) SCp[row] = s + b2v;
        }
    }
}

// ---------------------------------------------------------------------------
// head2: block (colgroup, b); 64 cols x 4 L-partitions per block. Pools bf16 Xb.
// ---------------------------------------------------------------------------
__global__ __launch_bounds__(256) void head2_kernel(
    const float* __restrict__ SCp, const ushort* __restrict__ Xb,
    float* __restrict__ outp)
{
    int cg = blockIdx.x, b = blockIdx.y;
    int tid = threadIdx.x;
    __shared__ float wbuf[L_];
    __shared__ float r1[4], r2[4];
    __shared__ float part[4][64];
    const float* s = SCp + (size_t)b * L_;

    float m = -1e30f;
    for (int j = tid; j < L_; j += 256) m = fmaxf(m, s[j]);
#pragma unroll
    for (int o = 1; o < 64; o <<= 1) m = fmaxf(m, __shfl_xor(m, o));
    if ((tid & 63) == 0) r1[tid >> 6] = m;
    __syncthreads();
    m = fmaxf(fmaxf(r1[0], r1[1]), fmaxf(r1[2], r1[3]));

    float sum = 0.f;
    for (int j = tid; j < L_; j += 256) {
        float e = __expf(s[j] - m);
        wbuf[j] = e;
        sum += e;
    }
#pragma unroll
    for (int o = 1; o < 64; o <<= 1) sum += __shfl_xor(sum, o);
    if ((tid & 63) == 0) r2[tid >> 6] = sum;
    __syncthreads();
    float inv = 1.0f / (r2[0] + r2[1] + r2[2] + r2[3]);

    int c = tid & 63, pt = tid >> 6;
    int col = cg * 64 + c;
    float acc = 0.f;
    const ushort* xb = Xb + (size_t)b * L_ * D_ + col;
    for (int l = pt; l < L_; l += 4) acc += wbuf[l] * bu2f(xb[(size_t)l * D_]);
    part[pt][c] = acc;
    __syncthreads();
    if (pt == 0)
        outp[b * D_ + col] = (part[0][c] + part[1][c] + part[2][c] + part[3][c]) * inv;
}

// ---------------------------------------------------------------------------
extern "C" void kernel_launch(void* const* d_in, const int* in_sizes, int n_in,
                              void* d_out, int out_size, void* d_ws, size_t ws_size,
                              hipStream_t stream)
{
    const float* gene   = (const float*)d_in[0];
    const float* coords = (const float*)d_in[1];
    const float* w_in   = (const float*)d_in[2];
    const float* b_in   = (const float*)d_in[3];
    const float* w_cls  = (const float*)d_in[4];
    const float* b_cls  = (const float*)d_in[5];
    const float* qkv_w  = (const float*)d_in[6];
    const float* qkv_b  = (const float*)d_in[7];
    const float* ln1_g  = (const float*)d_in[8];
    const float* ln1_b  = (const float*)d_in[9];
    const float* ffn_w1 = (const float*)d_in[10];
    const float* ffn_b1 = (const float*)d_in[11];
    const float* ffn_w2 = (const float*)d_in[12];
    const float* ffn_b2 = (const float*)d_in[13];
    const float* ln2_g  = (const float*)d_in[14];
    const float* ln2_b  = (const float*)d_in[15];
    const float* th1_w  = (const float*)d_in[16];
    const float* th1_b  = (const float*)d_in[17];
    const float* bn_g   = (const float*)d_in[18];
    const float* bn_b   = (const float*)d_in[19];
    const float* th2_w  = (const float*)d_in[20];
    const float* th2_b  = (const float*)d_in[21];
    float* out = (float*)d_out;

    const int ROWS = B_ * L_;   // 29248
    char* p = (char*)d_ws;
    ushort* AOb  = (ushort*)p; p += (size_t)MPAD * 256 * 2;
    ushort* Xb   = (ushort*)p; p += (size_t)MPAD * 256 * 2;
    ushort* SH   = (ushort*)p; p += (size_t)MPAD * 1024 * 2;
    ushort* qkvT = (ushort*)p; p += (size_t)NL_ * 768 * 256 * 2;
    ushort* W1P  = (ushort*)p; p += (size_t)NL_ * 1024 * 256 * 2;
    ushort* W2P  = (ushort*)p; p += (size_t)NL_ * 256 * 1024 * 2;
    ushort* th1T = (ushort*)p; p += (size_t)32 * 256 * 2;
    float*  SCp  = (float*)p;  p += (size_t)ROWS * 4;

    const int RB2 = MPAD / 256;                // 115 row blocks (256-row tiles)

    wcast_kernel<<<dim3(768 / 32, 256 / 32, NL_), dim3(32, 8), 0, stream>>>(qkv_w, qkvT, 256, 768);
    wpack_kernel<<<dim3(128, 1, NL_), 256, 0, stream>>>(ffn_w1, W1P, 256, 1024);
    wpack_kernel<<<dim3(128, 1, NL_), 256, 0, stream>>>(ffn_w2, W2P, 1024, 256);
    wcast_kernel<<<dim3(1, 8, 1), dim3(32, 8), 0, stream>>>(th1_w, th1T, 256, 32);

    sgemm_kernel<<<dim3(D_ / 64, (B_ * NT_) / 64), 256, 0, stream>>>(
        gene, w_in, b_in, Xb, B_ * NT_, D_, TOK_);
    cls_kernel<<<B_, 256, 0, stream>>>(coords, w_cls, b_cls, Xb);

    for (int l = 0; l < NL_; ++l) {
        mfma_gemm8<<<RB2 * (768 / 128), 512, 0, stream>>>(
            Xb, qkvT + (size_t)l * 768 * 256, qkv_b + l * 768, SH, 768, 256, 0);
        attn_kernel<<<dim3(H_, B_), 512, 0, stream>>>(SH, AOb);
        ffn_kernel<<<MPAD / 32, 512, 0, stream>>>(
            Xb, AOb, ln1_g + l * D_, ln1_b + l * D_,
            W1P + (size_t)l * 1024 * 256, W2P + (size_t)l * 256 * 1024,
            ffn_b1 + l * 1024, ffn_b2 + l * D_,
            ln2_g + l * D_, ln2_b + l * D_, Xb);
    }

    head1_kernel<<<MPAD / 128, 256, 0, stream>>>(
        Xb, th1T, th1_b, bn_g, bn_b, th2_w, th2_b, SCp);
    head2_kernel<<<dim3(4, B_), 256, 0, stream>>>(SCp, Xb, out);
}

// Round 11
// 613.426 us; speedup vs baseline: 1.1911x; 1.1911x over previous
//
#include <hip/hip_runtime.h>
#include <math.h>

#define B_   64
#define TOK_ 64
#define NT_  456
#define L_   457
#define D_   256
#define H_   8
#define HD_  32
#define FF_  1024
#define NL_  4
#define PH_  32
#define MPAD 29440   // 115 * 256 (rows padded for 256-row GEMM tiles; = 230*128)

typedef unsigned int uint;
typedef unsigned short ushort;
typedef __bf16 v8bf __attribute__((ext_vector_type(8)));
typedef __bf16 v4bf __attribute__((ext_vector_type(4)));
typedef short v4s __attribute__((ext_vector_type(4)));
typedef float v4f __attribute__((ext_vector_type(4)));

__device__ __forceinline__ float bu2f(ushort x) {
    return __uint_as_float(((uint)x) << 16);
}
__device__ __forceinline__ ushort f2bu(float f) {
    union { float f; uint u; } x; x.f = f;
    uint r = (x.u + 0x7fffu + ((x.u >> 16) & 1u)) >> 16;
    return (ushort)r;
}
__device__ __forceinline__ uint pack_bf2(float a, float b) {
#if defined(__HIP_DEVICE_COMPILE__) && __has_builtin(__builtin_amdgcn_cvt_pk_bf16_f32)
    typedef __bf16 bf2v __attribute__((ext_vector_type(2)));
    bf2v v = __builtin_amdgcn_cvt_pk_bf16_f32(a, b);
    return *(uint*)&v;
#else
    return (uint)f2bu(a) | ((uint)f2bu(b) << 16);
#endif
}

// K=16 bf16 MFMA (PV with register-resident P). Guarded for the host pass.
__device__ __forceinline__ v4f mfma16(uint2 a, uint2 b, v4f c) {
#if defined(__HIP_DEVICE_COMPILE__)
#if __has_builtin(__builtin_amdgcn_mfma_f32_16x16x16_bf16)
    return __builtin_amdgcn_mfma_f32_16x16x16_bf16(*(v4bf*)&a, *(v4bf*)&b, c, 0, 0, 0);
#else
    return __builtin_amdgcn_mfma_f32_16x16x16bf16_1k(*(v4s*)&a, *(v4s*)&b, c, 0, 0, 0);
#endif
#else
    (void)a; (void)b;
    return c;
#endif
}

// async global->LDS 16B copy; lds base wave-uniform, data at base + lane*16.
__device__ __forceinline__ void gload16(const void* g, void* l) {
    __builtin_amdgcn_global_load_lds(
        (const __attribute__((address_space(1))) void*)(unsigned long long)(uintptr_t)g,
        (__attribute__((address_space(3))) void*)(uint)(uintptr_t)l,
        16, 0, 0);
}

// ---------------------------------------------------------------------------
// Pipelined bf16 MFMA GEMM (T3+T4+T5): C[M,N] = A[M,K]·W^T[N,K] + bias.
// 256x128 tile, 8 waves (4x2), BK=32, ring-3 LDS buffer. Steady-state wait is
// s_waitcnt vmcnt(3); vmcnt(0) only at the last tile. setprio around MFMAs.
// ---------------------------------------------------------------------------
__global__ __launch_bounds__(512, 2) void mfma_gemm8(
    const ushort* __restrict__ A, const ushort* __restrict__ WT,
    const float* __restrict__ bias, ushort* __restrict__ Cout,
    int N, int K, int relu)
{
    __shared__ ushort lds[36864];   // 72 KB: A-ring 3x8192, B-ring 3x4096

    const int NK = K >> 5;

    // bijective XCD-aware remap (works for any grid size)
    int nwg = gridDim.x, orig = blockIdx.x;
    int qd = nwg >> 3, rd = nwg & 7;
    int xcd = orig & 7, wi = orig >> 3;
    int wgid = (xcd < rd ? xcd * (qd + 1) : rd * (qd + 1) + (xcd - rd) * qd) + wi;
    int nCB = N >> 7;
    int colblk = (wgid % nCB) << 7;
    int rowblk = (wgid / nCB) << 8;

    int tid = threadIdx.x;
    int wave = tid >> 6, lane = tid & 63;
    int wm = wave >> 1, wn = wave & 1;     // 4x2 wave grid: 64 rows x 64 cols each
    int fr = lane & 15, fq = lane >> 4;

    // ---- staging source pointers (pre-swizzled global addresses) ----
    const ushort* srcA0; const ushort* srcA1; const ushort* srcB0;
    {
        int idx = tid;
        int c = idx >> 3, G = (idx & 7) ^ (c & 7);
        srcA0 = A + (size_t)(rowblk + c * 2 + (G >> 2)) * K + (G & 3) * 8;
        idx = 512 + tid;
        c = idx >> 3; G = (idx & 7) ^ (c & 7);
        srcA1 = A + (size_t)(rowblk + c * 2 + (G >> 2)) * K + (G & 3) * 8;
        idx = tid;
        c = idx >> 3; G = (idx & 7) ^ (c & 7);
        srcB0 = WT + (size_t)(colblk + c * 2 + (G >> 2)) * K + (G & 3) * 8;
    }
    int duA0 = (wave * 64) * 8;          // ushort offsets (wave-uniform bases)
    int duA1 = (512 + wave * 64) * 8;
    int duB  = (wave * 64) * 8;

    // ---- fragment LDS offsets (ushort), swizzled to match staging ----
    int aoff[4], boff[4];
#pragma unroll
    for (int i = 0; i < 4; ++i) {
        int rl = wm * 64 + i * 16 + fr;
        int c = rl >> 1;
        aoff[i] = c * 64 + ((((rl & 1) * 4 + fq) ^ (c & 7)) * 8);
        rl = wn * 64 + i * 16 + fr;
        c = rl >> 1;
        boff[i] = c * 64 + ((((rl & 1) * 4 + fq) ^ (c & 7)) * 8);
    }

    v4f acc[4][4];
#pragma unroll
    for (int i = 0; i < 4; ++i)
#pragma unroll
        for (int j = 0; j < 4; ++j) acc[i][j] = (v4f)0.0f;

    // ---- prologue: stage tiles 0,1 into slots 0,1 (6 loads in flight) ----
#pragma unroll
    for (int t = 0; t < 2; ++t) {
        ushort* pa = lds + t * 8192;
        ushort* pb = lds + 24576 + t * 4096;
        gload16(srcA0 + t * 32, pa + duA0);
        gload16(srcA1 + t * 32, pa + duA1);
        gload16(srcB0 + t * 32, pb + duB);
    }

    // ---- main loop: one barrier period per BK=32 tile ----
    for (int t = 0; t < NK; ++t) {
        int slot = t % 3, pslot = (t + 2) % 3;
        const ushort* As = lds + slot * 8192;
        const ushort* Bs = lds + 24576 + slot * 4096;

        if (t < NK - 1) asm volatile("s_waitcnt vmcnt(3)" ::: "memory");
        else            asm volatile("s_waitcnt vmcnt(0)" ::: "memory");
        __builtin_amdgcn_s_barrier();
        asm volatile("" ::: "memory");

        if (t + 2 < NK) {   // stage tile t+2 into the slot freed by t-1
            ushort* pa = lds + pslot * 8192;
            ushort* pb = lds + 24576 + pslot * 4096;
            gload16(srcA0 + (t + 2) * 32, pa + duA0);
            gload16(srcA1 + (t + 2) * 32, pa + duA1);
            gload16(srcB0 + (t + 2) * 32, pb + duB);
        }

        v8bf av[4], bw[4];
#pragma unroll
        for (int i = 0; i < 4; ++i) av[i] = *(const v8bf*)(As + aoff[i]);
#pragma unroll
        for (int i = 0; i < 4; ++i) bw[i] = *(const v8bf*)(Bs + boff[i]);

        __builtin_amdgcn_s_setprio(1);
#pragma unroll
        for (int mi = 0; mi < 4; ++mi)
#pragma unroll
            for (int ni = 0; ni < 4; ++ni)
                acc[mi][ni] = __builtin_amdgcn_mfma_f32_16x16x32_bf16(
                    av[mi], bw[ni], acc[mi][ni], 0, 0, 0);
        __builtin_amdgcn_s_setprio(0);
    }

    // ---- epilogue: acc -> LDS (pitch 136) -> coalesced uint4 stores ----
    __syncthreads();
    {
        const int PIT = 136;
#pragma unroll
        for (int ni = 0; ni < 4; ++ni) {
            int col = wn * 64 + ni * 16 + fr;
            float bv = bias[colblk + col];
#pragma unroll
            for (int mi = 0; mi < 4; ++mi) {
                int row0 = wm * 64 + mi * 16 + fq * 4;
#pragma unroll
                for (int r2 = 0; r2 < 4; ++r2) {
                    float v = acc[mi][ni][r2] + bv;
                    if (relu) v = fmaxf(v, 0.f);
                    lds[(row0 + r2) * PIT + col] = f2bu(v);
                }
            }
        }
        __syncthreads();
#pragma unroll
        for (int i = 0; i < 8; ++i) {
            int u = tid + 512 * i;            // 0..4095 uint4 of the 256x128 tile
            int row = u >> 4, c8 = (u & 15) * 8;
            uint4 val = *(const uint4*)&lds[row * PIT + c8];
            *(uint4*)(Cout + (size_t)(rowblk + row) * N + colblk + c8) = val;
        }
    }
}

// ---------------------------------------------------------------------------
// Fused block tail v3 (R6 verified best): Xb <- LN2( LN1(Xb+AO) @FFN ).
//   u = LN1(Xb_old + AO)        [prologue, u -> Xs in FF1-swizzled layout]
//   H = relu(u@W1^T + b1)       [quarters in LDS, packed-frag W loads]
//   C = H@W2^T + b2             [acc2]
//   Xb = LN2(u + C)             [epilogue; u re-read from Xs]
// Replaces ln1 + ffn + ln2 (3 dispatches -> 1; -75 MB HBM/layer).
// Post-R7..R10 note: eighths/32-row variants all regressed (spills /
// barrier-bound); this 64-row quarters version is the converged optimum.
// ---------------------------------------------------------------------------
__global__ __launch_bounds__(512, 4) void ffn_kernel(
    const ushort* __restrict__ Xres, const ushort* __restrict__ AO,
    const float* __restrict__ l1g, const float* __restrict__ l1b,
    const ushort* __restrict__ W1P, const ushort* __restrict__ W2P,
    const float* __restrict__ b1, const float* __restrict__ b2,
    const float* __restrict__ l2g, const float* __restrict__ l2b,
    ushort* __restrict__ Xout)
{
    __shared__ ushort Xs[16384];      // u, 64r x 256k, gemm8-A swizzled (32 KB)
    __shared__ ushort Hs[64 * 264];   // H quarter 64r x 256c, pitch 264 (33 KB)

    int r0 = blockIdx.x * 64;
    int tid = threadIdx.x;
    int wave = tid >> 6, lane = tid & 63;
    int fr = lane & 15, fq = lane >> 4;

    // ---- prologue: u = LN1(Xres + AO), written to Xs (swizzled) ----
    {
        float4 g1 = *(const float4*)(l1g + lane * 4);
        float4 be1 = *(const float4*)(l1b + lane * 4);
        ushort4 xr[8], ar[8];
#pragma unroll
        for (int rr = 0; rr < 8; ++rr) {
            size_t off = (size_t)(r0 + wave * 8 + rr) * 256 + lane * 4;
            xr[rr] = *(const ushort4*)(Xres + off);
            ar[rr] = *(const ushort4*)(AO + off);
        }
#pragma unroll
        for (int rr = 0; rr < 8; ++rr) {
            int row = wave * 8 + rr;
            float4 v;
            v.x = bu2f(xr[rr].x) + bu2f(ar[rr].x);
            v.y = bu2f(xr[rr].y) + bu2f(ar[rr].y);
            v.z = bu2f(xr[rr].z) + bu2f(ar[rr].z);
            v.w = bu2f(xr[rr].w) + bu2f(ar[rr].w);
            float s = v.x + v.y + v.z + v.w;
#pragma unroll
            for (int o = 1; o < 64; o <<= 1) s += __shfl_xor(s, o);
            float mean = s * (1.0f / 256.0f);
            float4 d;
            d.x = v.x - mean; d.y = v.y - mean; d.z = v.z - mean; d.w = v.w - mean;
            float sq = d.x * d.x + d.y * d.y + d.z * d.z + d.w * d.w;
#pragma unroll
            for (int o = 1; o < 64; o <<= 1) sq += __shfl_xor(sq, o);
            float rstd = rsqrtf(sq * (1.0f / 256.0f) + 1e-5f);
            ushort4 hb;
            hb.x = f2bu(d.x * rstd * g1.x + be1.x);
            hb.y = f2bu(d.y * rstd * g1.y + be1.y);
            hb.z = f2bu(d.z * rstd * g1.z + be1.z);
            hb.w = f2bu(d.w * rstd * g1.w + be1.w);
            // swizzled Xs address for (row, cols lane*4..lane*4+3)
            int kt = lane >> 3, g = (lane >> 1) & 3, c = row >> 1;
            int Gp = ((row & 1) * 4 + g) ^ (c & 7);
            int addr = kt * 2048 + (c * 8 + Gp) * 8 + (lane & 1) * 4;
            *(uint2*)&Xs[addr] = *(uint2*)&hb;
        }
    }

    // A-frag offsets within a k-tile (FF1; rows 0..63)
    int aoffs[4];
#pragma unroll
    for (int mi = 0; mi < 4; ++mi) {
        int ar2 = mi * 16 + fr, c = ar2 >> 1;
        aoffs[mi] = c * 64 + ((((ar2 & 1) * 4 + fq) ^ (c & 7)) * 8);
    }
    int wm2 = wave >> 2, wn2 = wave & 3;   // FF2 wave grid 2x4

    v4f acc2[2][4];
#pragma unroll
    for (int i = 0; i < 2; ++i)
#pragma unroll
        for (int j = 0; j < 4; ++j) acc2[i][j] = (v4f)0.0f;

    __syncthreads();

#pragma unroll
    for (int q = 0; q < 4; ++q) {
        // ---- FF1: this wave's 32 H-cols of quarter q ----
        v4f acc1[4][2];
#pragma unroll
        for (int i = 0; i < 4; ++i)
#pragma unroll
            for (int j = 0; j < 2; ++j) acc1[i][j] = (v4f)0.0f;

        const ushort* w1p = W1P + (size_t)((q * 16 + wave * 2) * 8) * 64 * 8;
#pragma unroll
        for (int kc = 0; kc < 8; ++kc) {
            v8bf bf0 = *(const v8bf*)(w1p + ((size_t)kc * 64 + lane) * 8);
            v8bf bf1 = *(const v8bf*)(w1p + ((size_t)(8 + kc) * 64 + lane) * 8);
            v8bf a[4];
#pragma unroll
            for (int mi = 0; mi < 4; ++mi)
                a[mi] = *(const v8bf*)(Xs + kc * 2048 + aoffs[mi]);
#pragma unroll
            for (int mi = 0; mi < 4; ++mi) {
                acc1[mi][0] = __builtin_amdgcn_mfma_f32_16x16x32_bf16(
                    a[mi], bf0, acc1[mi][0], 0, 0, 0);
                acc1[mi][1] = __builtin_amdgcn_mfma_f32_16x16x32_bf16(
                    a[mi], bf1, acc1[mi][1], 0, 0, 0);
            }
        }
        float b1v[2];
#pragma unroll
        for (int ni = 0; ni < 2; ++ni)
            b1v[ni] = b1[q * 256 + wave * 32 + ni * 16 + fr];

        if (q) __syncthreads();            // prev quarter's FF2 reads done
        // ---- relu + bias, write H quarter to LDS ----
#pragma unroll
        for (int ni = 0; ni < 2; ++ni) {
            int col = wave * 32 + ni * 16 + fr;
#pragma unroll
            for (int mi = 0; mi < 4; ++mi) {
                int row0 = mi * 16 + fq * 4;
#pragma unroll
                for (int r2 = 0; r2 < 4; ++r2)
                    Hs[(row0 + r2) * 264 + col] =
                        f2bu(fmaxf(acc1[mi][ni][r2] + b1v[ni], 0.f));
            }
        }
        __syncthreads();

        // ---- FF2 partial: acc2 += H_q @ W2^T[:, q*256 .. +256) ----
#pragma unroll
        for (int kk = 0; kk < 8; ++kk) {
            v8bf bw2[4];
#pragma unroll
            for (int ni = 0; ni < 4; ++ni)
                bw2[ni] = *(const v8bf*)(W2P +
                    (size_t)((((wn2 * 4 + ni) * 32 + q * 8 + kk) * 64 + lane)) * 8);
            v8bf a2[2];
#pragma unroll
            for (int mi = 0; mi < 2; ++mi)
                a2[mi] = *(const v8bf*)(Hs +
                    (wm2 * 32 + mi * 16 + fr) * 264 + kk * 32 + fq * 8);
#pragma unroll
            for (int mi = 0; mi < 2; ++mi)
#pragma unroll
                for (int ni = 0; ni < 4; ++ni)
                    acc2[mi][ni] = __builtin_amdgcn_mfma_f32_16x16x32_bf16(
                        a2[mi], bw2[ni], acc2[mi][ni], 0, 0, 0);
        }
    }

    // ---- epilogue: C=acc2+b2 -> Hs; then Xb = LN2(u + C) ----
    __syncthreads();
    {
        float b2v[4];
#pragma unroll
        for (int ni = 0; ni < 4; ++ni) b2v[ni] = b2[wn2 * 64 + ni * 16 + fr];
#pragma unroll
        for (int ni = 0; ni < 4; ++ni) {
            int col = wn2 * 64 + ni * 16 + fr;
#pragma unroll
            for (int mi = 0; mi < 2; ++mi) {
                int row0 = wm2 * 32 + mi * 16 + fq * 4;
#pragma unroll
                for (int r2 = 0; r2 < 4; ++r2)
                    Hs[(row0 + r2) * 264 + col] = f2bu(acc2[mi][ni][r2] + b2v[ni]);
            }
        }
        __syncthreads();

        float4 g2 = *(const float4*)(l2g + lane * 4);
        float4 be2 = *(const float4*)(l2b + lane * 4);
#pragma unroll
        for (int rr = 0; rr < 8; ++rr) {
            int row = wave * 8 + rr;
            ushort4 cv = *(const ushort4*)&Hs[row * 264 + lane * 4];
            int kt = lane >> 3, g = (lane >> 1) & 3, c = row >> 1;
            int Gp = ((row & 1) * 4 + g) ^ (c & 7);
            int addr = kt * 2048 + (c * 8 + Gp) * 8 + (lane & 1) * 4;
            uint2 uu = *(const uint2*)&Xs[addr];
            ushort4 uv = *(ushort4*)&uu;
            float4 v;
            v.x = bu2f(cv.x) + bu2f(uv.x);
            v.y = bu2f(cv.y) + bu2f(uv.y);
            v.z = bu2f(cv.z) + bu2f(uv.z);
            v.w = bu2f(cv.w) + bu2f(uv.w);
            float s = v.x + v.y + v.z + v.w;
#pragma unroll
            for (int o = 1; o < 64; o <<= 1) s += __shfl_xor(s, o);
            float mean = s * (1.0f / 256.0f);
            float4 d;
            d.x = v.x - mean; d.y = v.y - mean; d.z = v.z - mean; d.w = v.w - mean;
            float sq = d.x * d.x + d.y * d.y + d.z * d.z + d.w * d.w;
#pragma unroll
            for (int o = 1; o < 64; o <<= 1) sq += __shfl_xor(sq, o);
            float rstd = rsqrtf(sq * (1.0f / 256.0f) + 1e-5f);
            ushort4 hb;
            hb.x = f2bu(d.x * rstd * g2.x + be2.x);
            hb.y = f2bu(d.y * rstd * g2.y + be2.y);
            hb.z = f2bu(d.z * rstd * g2.z + be2.z);
            hb.w = f2bu(d.w * rstd * g2.w + be2.w);
            *(ushort4*)(Xout + (size_t)(r0 + row) * 256 + lane * 4) = hb;
        }
    }
}

// ---------------------------------------------------------------------------
// Pack fp32 W[K][N] (one layer per blockIdx.z) into MFMA B-frag order:
// P[((grp*(K/32)+kc)*64+lane)*8+e] = bf16(W[(kc*32+(lane>>4)*8+e)*N + grp*16+(lane&15)])
// ---------------------------------------------------------------------------
__global__ __launch_bounds__(256) void wpack_kernel(
    const float* __restrict__ W, ushort* __restrict__ P, int K, int N)
{
    int KC = K >> 5;
    int total = (N >> 4) * KC * 64;
    const float* Wl = W + (size_t)blockIdx.z * K * N;
    ushort* Pl = P + (size_t)blockIdx.z * K * N;
    int gid = blockIdx.x * 256 + threadIdx.x;
    if (gid >= total) return;
    int lane = gid & 63;
    int t = gid >> 6;
    int kc = t % KC, grp = t / KC;
    int n = grp * 16 + (lane & 15);
    int k0 = kc * 32 + (lane >> 4) * 8;
    float v[8];
#pragma unroll
    for (int e = 0; e < 8; ++e) v[e] = Wl[(size_t)(k0 + e) * N + n];
    uint4 o;
    o.x = pack_bf2(v[0], v[1]);
    o.y = pack_bf2(v[2], v[3]);
    o.z = pack_bf2(v[4], v[5]);
    o.w = pack_bf2(v[6], v[7]);
    *(uint4*)&Pl[(size_t)gid * 8] = o;
}

// ---------------------------------------------------------------------------
__global__ __launch_bounds__(256) void wcast_kernel(
    const float* __restrict__ W, ushort* __restrict__ WT, int K, int N)
{
    __shared__ float t[32][33];
    const float* Wl = W + (size_t)blockIdx.z * K * N;
    ushort* WTl = WT + (size_t)blockIdx.z * K * N;
    int n0 = blockIdx.x * 32, k0 = blockIdx.y * 32;
    int tx = threadIdx.x, ty = threadIdx.y;
#pragma unroll
    for (int r = 0; r < 32; r += 8)
        t[ty + r][tx] = Wl[(size_t)(k0 + ty + r) * N + n0 + tx];
    __syncthreads();
#pragma unroll
    for (int r = 0; r < 32; r += 8)
        WTl[(size_t)(n0 + ty + r) * K + k0 + tx] = f2bu(t[tx][ty + r]);
}

// ---------------------------------------------------------------------------
// fp32 SGEMM for the embed GEMM only; row-remap; writes bf16 Xb only.
// ---------------------------------------------------------------------------
__global__ __launch_bounds__(256) void sgemm_kernel(
    const float* __restrict__ A, const float* __restrict__ W,
    const float* __restrict__ bias, ushort* __restrict__ Cb,
    int M, int N, int K)
{
    __shared__ float As_[16][64];
    __shared__ float Bs_[16][64];
    int tid = threadIdx.x;
    int rowblk = blockIdx.y * 64;
    int colblk = blockIdx.x * 64;
    int a_row = tid & 63, a_q = tid >> 6;
    int b_kr = tid >> 4, b_cg = tid & 15;
    int rm = tid >> 4, cn = tid & 15;
    float acc[4][4] = {};
    const float* Aptr = A + (size_t)(rowblk + a_row) * K;
    for (int kt = 0; kt < K; kt += 16) {
        float4 av = *(const float4*)(Aptr + kt + a_q * 4);
        float4 bv = *(const float4*)(W + (size_t)(kt + b_kr) * N + colblk + b_cg * 4);
        As_[a_q * 4 + 0][a_row] = av.x;
        As_[a_q * 4 + 1][a_row] = av.y;
        As_[a_q * 4 + 2][a_row] = av.z;
        As_[a_q * 4 + 3][a_row] = av.w;
        *(float4*)&Bs_[b_kr][b_cg * 4] = bv;
        __syncthreads();
#pragma unroll
        for (int kk = 0; kk < 16; ++kk) {
            float4 a4 = *(const float4*)&As_[kk][rm * 4];
            float4 b4 = *(const float4*)&Bs_[kk][cn * 4];
            float ar[4] = {a4.x, a4.y, a4.z, a4.w};
            float br[4] = {b4.x, b4.y, b4.z, b4.w};
#pragma unroll
            for (int i = 0; i < 4; ++i)
#pragma unroll
                for (int j = 0; j < 4; ++j) acc[i][j] += ar[i] * br[j];
        }
        __syncthreads();
    }
    float4 bv = *(const float4*)(bias + colblk + cn * 4);
    float bb[4] = {bv.x, bv.y, bv.z, bv.w};
#pragma unroll
    for (int i = 0; i < 4; ++i) {
        int grow = rowblk + rm * 4 + i;
        size_t orow = (size_t)(grow + grow / NT_ + 1);
        ushort4 h;
        h.x = f2bu(acc[i][0] + bb[0]);
        h.y = f2bu(acc[i][1] + bb[1]);
        h.z = f2bu(acc[i][2] + bb[2]);
        h.w = f2bu(acc[i][3] + bb[3]);
        *(ushort4*)(Cb + orow * N + colblk + cn * 4) = h;
    }
}

__global__ __launch_bounds__(256) void cls_kernel(
    const float* __restrict__ coords, const float* __restrict__ w_cls,
    const float* __restrict__ b_cls, ushort* __restrict__ Xb)
{
    int b = blockIdx.x;
    int t = threadIdx.x;
    float c0 = coords[b * 3 + 0], c1 = coords[b * 3 + 1], c2 = coords[b * 3 + 2];
    float v = c0 * w_cls[t] + c1 * w_cls[D_ + t] + c2 * w_cls[2 * D_ + t] + b_cls[t];
    Xb[(size_t)b * L_ * D_ + t] = f2bu(v);
}

// ---------------------------------------------------------------------------
// MFMA attention v7 (banded alibi): one block per (b,h), 512 threads.
// (R1 exact version -- verified best.)
// ---------------------------------------------------------------------------
__global__ __launch_bounds__(512) void attn_kernel(
    const ushort* __restrict__ qkv, ushort* __restrict__ out)
{
    __shared__ __align__(16) ushort Ks[464][40];    // 36.3 KB
    __shared__ __align__(16) ushort Vt[32][488];    // 30.5 KB

    int h = blockIdx.x, b = blockIdx.y;
    int tid = threadIdx.x;
    int wave = tid >> 6, lane = tid & 63;
    int fr = lane & 15, fq = lane >> 4;
    const float scale2 = 0.17677669529663687f * 1.4426950408889634f;
    float slope2 = ((h < 4) ? 1.0f : 0.5f) * 1.4426950408889634f;
    int W = (h < 4) ? 32 : 64;   // band half-width (wave-uniform)
    const ushort* base = qkv + (size_t)b * L_ * 768;

    for (int j = tid >> 2; j < 464; j += 128) {
        int c8 = (tid & 3) * 8;
        uint4 u = make_uint4(0u, 0u, 0u, 0u);
        if (j < L_) u = *(const uint4*)(base + (size_t)j * 768 + 256 + h * 32 + c8);
        *(uint4*)&Ks[j][c8] = u;
    }
    for (int m = wave; m < 32; m += 8) {
        int dg = (m >> 3) * 8, jb = m & 7;
        int j = jb * 64 + lane;
        uint4 u = make_uint4(0u, 0u, 0u, 0u);
        if (j < L_) u = *(const uint4*)(base + (size_t)j * 768 + 512 + h * 32 + dg);
        if (j < 488) {
            const ushort* pu = (const ushort*)&u;
#pragma unroll
            for (int e = 0; e < 8; ++e) Vt[dg + e][j] = pu[e];
        }
    }
    __syncthreads();

    for (int pr = wave; pr < 15; pr += 8) {
        int q0 = pr * 32;
        int twoB = (pr < 14);
        int kclo = max(0, (q0 - W) >> 5);
        int kchi = min(13, (q0 + 31 + W) >> 5);      // last full 32-chunk
        int doTail = (q0 + 31 + W >= 448);
        uint4 quA = *(const uint4*)(base + (size_t)(q0 + fr) * 768 + h * 32 + fq * 8);
        v8bf qfA = *(v8bf*)&quA;
        uint4 quB = *(const uint4*)(base + (size_t)(q0 + 16 + fr) * 768 + h * 32 + fq * 8);
        v8bf qfB = *(v8bf*)&quB;
        float fqAq = (float)(q0 + fr);
        float fqBq = fqAq + 16.0f;
        float psA = 0.f, psB = 0.f;
        v4f oA0 = (v4f)0.0f, oA1 = (v4f)0.0f, oB0 = (v4f)0.0f, oB1 = (v4f)0.0f;

        for (int kc = kclo; kc <= kchi; ++kc) {
            int kb = kc * 32;
            v8bf kf0 = *(const v8bf*)&Ks[kb + fr][fq * 8];
            v8bf kf1 = *(const v8bf*)&Ks[kb + 16 + fr][fq * 8];
            uint2 va0 = *(const uint2*)&Vt[fr][kb + fq * 4];
            uint2 va1 = *(const uint2*)&Vt[16 + fr][kb + fq * 4];
            uint2 vb0 = *(const uint2*)&Vt[fr][kb + 16 + fq * 4];
            uint2 vb1 = *(const uint2*)&Vt[16 + fr][kb + 16 + fq * 4];
            float ke = (float)(kb + 4 * fq);

            v4f dA0 = (v4f)0.0f, dA1 = (v4f)0.0f;
            dA0 = __builtin_amdgcn_mfma_f32_16x16x32_bf16(kf0, qfA, dA0, 0, 0, 0);
            dA1 = __builtin_amdgcn_mfma_f32_16x16x32_bf16(kf1, qfA, dA1, 0, 0, 0);
            {
                float dl0 = fqAq - ke, dl1 = dl0 - 16.0f;
                float pe[4], po[4];
#pragma unroll
                for (int r = 0; r < 4; ++r) {
                    pe[r] = exp2f(fmaf(dA0[r], scale2, -slope2 * fabsf(dl0 - (float)r)));
                    po[r] = exp2f(fmaf(dA1[r], scale2, -slope2 * fabsf(dl1 - (float)r)));
                    psA += pe[r] + po[r];
                }
                uint2 ue, uo;
                ue.x = pack_bf2(pe[0], pe[1]); ue.y = pack_bf2(pe[2], pe[3]);
                uo.x = pack_bf2(po[0], po[1]); uo.y = pack_bf2(po[2], po[3]);
                oA0 = mfma16(va0, ue, oA0);
                oA1 = mfma16(va1, ue, oA1);
                oA0 = mfma16(vb0, uo, oA0);
                oA1 = mfma16(vb1, uo, oA1);
            }
            if (twoB) {
                v4f dB0 = (v4f)0.0f, dB1 = (v4f)0.0f;
                dB0 = __builtin_amdgcn_mfma_f32_16x16x32_bf16(kf0, qfB, dB0, 0, 0, 0);
                dB1 = __builtin_amdgcn_mfma_f32_16x16x32_bf16(kf1, qfB, dB1, 0, 0, 0);
                float dl0 = fqBq - ke, dl1 = dl0 - 16.0f;
                float pe[4], po[4];
#pragma unroll
                for (int r = 0; r < 4; ++r) {
                    pe[r] = exp2f(fmaf(dB0[r], scale2, -slope2 * fabsf(dl0 - (float)r)));
                    po[r] = exp2f(fmaf(dB1[r], scale2, -slope2 * fabsf(dl1 - (float)r)));
                    psB += pe[r] + po[r];
                }
                uint2 ue, uo;
                ue.x = pack_bf2(pe[0], pe[1]); ue.y = pack_bf2(pe[2], pe[3]);
                uo.x = pack_bf2(po[0], po[1]); uo.y = pack_bf2(po[2], po[3]);
                oB0 = mfma16(va0, ue, oB0);
                oB1 = mfma16(va1, ue, oB1);
                oB0 = mfma16(vb0, uo, oB0);
                oB1 = mfma16(vb1, uo, oB1);
            }
        }
        // tail chunk: k 448..463 (only if band reaches it)
        if (doTail) {
            v8bf kf0 = *(const v8bf*)&Ks[448 + fr][fq * 8];
            uint2 va0 = *(const uint2*)&Vt[fr][448 + fq * 4];
            uint2 va1 = *(const uint2*)&Vt[16 + fr][448 + fq * 4];
            v4f dA0 = (v4f)0.0f;
            dA0 = __builtin_amdgcn_mfma_f32_16x16x32_bf16(kf0, qfA, dA0, 0, 0, 0);
            float pe[4];
#pragma unroll
            for (int r = 0; r < 4; ++r) {
                int k = 448 + 4 * fq + r;
                pe[r] = (k < L_)
                    ? exp2f(fmaf(dA0[r], scale2, -slope2 * fabsf(fqAq - (float)k))) : 0.f;
                psA += pe[r];
            }
            uint2 ue;
            ue.x = pack_bf2(pe[0], pe[1]); ue.y = pack_bf2(pe[2], pe[3]);
            oA0 = mfma16(va0, ue, oA0);
            oA1 = mfma16(va1, ue, oA1);
            if (twoB) {
                v4f dB0 = (v4f)0.0f;
                dB0 = __builtin_amdgcn_mfma_f32_16x16x32_bf16(kf0, qfB, dB0, 0, 0, 0);
                float pf[4];
#pragma unroll
                for (int r = 0; r < 4; ++r) {
                    int k = 448 + 4 * fq + r;
                    pf[r] = (k < L_)
                        ? exp2f(fmaf(dB0[r], scale2, -slope2 * fabsf(fqBq - (float)k))) : 0.f;
                    psB += pf[r];
                }
                uint2 ub;
                ub.x = pack_bf2(pf[0], pf[1]); ub.y = pack_bf2(pf[2], pf[3]);
                oB0 = mfma16(va0, ub, oB0);
                oB1 = mfma16(va1, ub, oB1);
            }
        }

        psA += __shfl_xor(psA, 16);
        psA += __shfl_xor(psA, 32);
        psB += __shfl_xor(psB, 16);
        psB += __shfl_xor(psB, 32);
        {
            int q = q0 + fr;
            if (q < L_) {
                float inv = 1.0f / psA;
                uint2 w0, w1;
                w0.x = pack_bf2(oA0[0] * inv, oA0[1] * inv);
                w0.y = pack_bf2(oA0[2] * inv, oA0[3] * inv);
                w1.x = pack_bf2(oA1[0] * inv, oA1[1] * inv);
                w1.y = pack_bf2(oA1[2] * inv, oA1[3] * inv);
                ushort* op = out + (size_t)(b * L_ + q) * D_ + h * 32;
                *(uint2*)(op + fq * 4) = w0;
                *(uint2*)(op + 16 + fq * 4) = w1;
            }
        }
        if (twoB) {
            int q = q0 + 16 + fr;
            if (q < L_) {
                float inv = 1.0f / psB;
                uint2 w0, w1;
                w0.x = pack_bf2(oB0[0] * inv, oB0[1] * inv);
                w0.y = pack_bf2(oB0[2] * inv, oB0[3] * inv);
                w1.x = pack_bf2(oB1[0] * inv, oB1[1] * inv);
                w1.y = pack_bf2(oB1[2] * inv, oB1[3] * inv);
                ushort* op = out + (size_t)(b * L_ + q) * D_ + h * 32;
                *(uint2*)(op + fq * 4) = w0;
                *(uint2*)(op + 16 + fq * 4) = w1;
            }
        }
    }
}

// ---------------------------------------------------------------------------
// head1 via MFMA: SCp[row] = gelu(bn(Xb@th1_w + b1)) @ th2_w + b2.
// ---------------------------------------------------------------------------
__global__ __launch_bounds__(256) void head1_kernel(
    const ushort* __restrict__ Xb, const ushort* __restrict__ th1T,
    const float* __restrict__ b1, const float* __restrict__ bng,
    const float* __restrict__ bnb, const float* __restrict__ w2,
    const float* __restrict__ b2, float* __restrict__ SCp)
{
    __shared__ ushort As[128 * 32];
    __shared__ ushort Bs[32 * 264];
    int tid = threadIdx.x;
    int wave = tid >> 6, lane = tid & 63;
    int fr = lane & 15, fq = lane >> 4;
    int rowblk = blockIdx.x * 128;
    int scol = fq ^ (lane & 3) ^ ((lane >> 2) & 1);

    for (int i = tid; i < 1024; i += 256) {
        int r = i >> 5, c8 = (i & 31) * 8;
        *(uint4*)&Bs[r * 264 + c8] = *(const uint4*)(th1T + r * 256 + c8);
    }

    int c0 = wave * 64 + lane;
    int r0 = c0 >> 2, k0g = (c0 & 3) ^ (r0 & 3) ^ ((r0 >> 2) & 1);
    int c1 = 256 + c0;
    int r1 = c1 >> 2, k1g = (c1 & 3) ^ (r1 & 3) ^ ((r1 >> 2) & 1);
    const ushort* Ag0 = Xb + (size_t)(rowblk + r0) * 256 + k0g * 8;
    const ushort* Ag1 = Xb + (size_t)(rowblk + r1) * 256 + k1g * 8;
    ushort* lA0 = As + (size_t)(wave * 64) * 8;
    ushort* lA1 = As + (size_t)(256 + wave * 64) * 8;

    v4f acc[2][2];
#pragma unroll
    for (int i = 0; i < 2; ++i)
#pragma unroll
        for (int j = 0; j < 2; ++j) acc[i][j] = (v4f)0.0f;

    for (int kt = 0; kt < 256; kt += 32) {
        gload16(Ag0 + kt, lA0);
        gload16(Ag1 + kt, lA1);
        __syncthreads();
        v8bf a[2], bfr[2];
#pragma unroll
        for (int mi = 0; mi < 2; ++mi)
            a[mi] = *(const v8bf*)(As + (size_t)((wave * 2 + mi) * 16 + fr) * 32 + scol * 8);
#pragma unroll
        for (int ni = 0; ni < 2; ++ni)
            bfr[ni] = *(const v8bf*)(Bs + (size_t)(ni * 16 + fr) * 264 + kt + fq * 8);
#pragma unroll
        for (int mi = 0; mi < 2; ++mi)
#pragma unroll
            for (int ni = 0; ni < 2; ++ni)
                acc[mi][ni] = __builtin_amdgcn_mfma_f32_16x16x32_bf16(
                    a[mi], bfr[ni], acc[mi][ni], 0, 0, 0);
        __syncthreads();
    }

    const float bnr = 0.9999950000374997f;  // rsqrt(1+1e-5)
    float b1v[2], bsv[2], bbv[2], w2v[2];
#pragma unroll
    for (int ni = 0; ni < 2; ++ni) {
        int j = ni * 16 + fr;
        b1v[ni] = b1[j];
        bsv[ni] = bng[j] * bnr;
        bbv[ni] = bnb[j];
        w2v[ni] = w2[j];
    }
    const float gc = 0.7978845608028654f;
    float b2v = b2[0];
#pragma unroll
    for (int mi = 0; mi < 2; ++mi) {
#pragma unroll
        for (int r = 0; r < 4; ++r) {
            float s = 0.f;
#pragma unroll
            for (int ni = 0; ni < 2; ++ni) {
                float hb = (acc[mi][ni][r] + b1v[ni]) * bsv[ni] + bbv[ni];
                float t = tanhf(gc * (hb + 0.044715f * hb * hb * hb));
                s += 0.5f * hb * (1.0f + t) * w2v[ni];
            }
#pragma unroll
            for (int o = 1; o < 16; o <<= 1) s += __shfl_xor(s, o);
            int row = rowblk + (wave * 2 + mi) * 16 + fq * 4 + r;
            if (fr == 0 && row < B_ * L_) SCp[row] = s + b2v;
        }
    }
}

// ---------------------------------------------------------------------------
// head2: block (colgroup, b); 64 cols x 4 L-partitions per block. Pools bf16 Xb.
// ---------------------------------------------------------------------------
__global__ __launch_bounds__(256) void head2_kernel(
    const float* __restrict__ SCp, const ushort* __restrict__ Xb,
    float* __restrict__ outp)
{
    int cg = blockIdx.x, b = blockIdx.y;
    int tid = threadIdx.x;
    __shared__ float wbuf[L_];
    __shared__ float r1[4], r2[4];
    __shared__ float part[4][64];
    const float* s = SCp + (size_t)b * L_;

    float m = -1e30f;
    for (int j = tid; j < L_; j += 256) m = fmaxf(m, s[j]);
#pragma unroll
    for (int o = 1; o < 64; o <<= 1) m = fmaxf(m, __shfl_xor(m, o));
    if ((tid & 63) == 0) r1[tid >> 6] = m;
    __syncthreads();
    m = fmaxf(fmaxf(r1[0], r1[1]), fmaxf(r1[2], r1[3]));

    float sum = 0.f;
    for (int j = tid; j < L_; j += 256) {
        float e = __expf(s[j] - m);
        wbuf[j] = e;
        sum += e;
    }
#pragma unroll
    for (int o = 1; o < 64; o <<= 1) sum += __shfl_xor(sum, o);
    if ((tid & 63) == 0) r2[tid >> 6] = sum;
    __syncthreads();
    float inv = 1.0f / (r2[0] + r2[1] + r2[2] + r2[3]);

    int c = tid & 63, pt = tid >> 6;
    int col = cg * 64 + c;
    float acc = 0.f;
    const ushort* xb = Xb + (size_t)b * L_ * D_ + col;
    for (int l = pt; l < L_; l += 4) acc += wbuf[l] * bu2f(xb[(size_t)l * D_]);
    part[pt][c] = acc;
    __syncthreads();
    if (pt == 0)
        outp[b * D_ + col] = (part[0][c] + part[1][c] + part[2][c] + part[3][c]) * inv;
}

// ---------------------------------------------------------------------------
extern "C" void kernel_launch(void* const* d_in, const int* in_sizes, int n_in,
                              void* d_out, int out_size, void* d_ws, size_t ws_size,
                              hipStream_t stream)
{
    const float* gene   = (const float*)d_in[0];
    const float* coords = (const float*)d_in[1];
    const float* w_in   = (const float*)d_in[2];
    const float* b_in   = (const float*)d_in[3];
    const float* w_cls  = (const float*)d_in[4];
    const float* b_cls  = (const float*)d_in[5];
    const float* qkv_w  = (const float*)d_in[6];
    const float* qkv_b  = (const float*)d_in[7];
    const float* ln1_g  = (const float*)d_in[8];
    const float* ln1_b  = (const float*)d_in[9];
    const float* ffn_w1 = (const float*)d_in[10];
    const float* ffn_b1 = (const float*)d_in[11];
    const float* ffn_w2 = (const float*)d_in[12];
    const float* ffn_b2 = (const float*)d_in[13];
    const float* ln2_g  = (const float*)d_in[14];
    const float* ln2_b  = (const float*)d_in[15];
    const float* th1_w  = (const float*)d_in[16];
    const float* th1_b  = (const float*)d_in[17];
    const float* bn_g   = (const float*)d_in[18];
    const float* bn_b   = (const float*)d_in[19];
    const float* th2_w  = (const float*)d_in[20];
    const float* th2_b  = (const float*)d_in[21];
    float* out = (float*)d_out;

    const int ROWS = B_ * L_;   // 29248
    char* p = (char*)d_ws;
    ushort* AOb  = (ushort*)p; p += (size_t)MPAD * 256 * 2;
    ushort* Xb   = (ushort*)p; p += (size_t)MPAD * 256 * 2;
    ushort* SH   = (ushort*)p; p += (size_t)MPAD * 1024 * 2;
    ushort* qkvT = (ushort*)p; p += (size_t)NL_ * 768 * 256 * 2;
    ushort* W1P  = (ushort*)p; p += (size_t)NL_ * 1024 * 256 * 2;
    ushort* W2P  = (ushort*)p; p += (size_t)NL_ * 256 * 1024 * 2;
    ushort* th1T = (ushort*)p; p += (size_t)32 * 256 * 2;
    float*  SCp  = (float*)p;  p += (size_t)ROWS * 4;

    const int RB2 = MPAD / 256;                // 115 row blocks (256-row tiles)

    wcast_kernel<<<dim3(768 / 32, 256 / 32, NL_), dim3(32, 8), 0, stream>>>(qkv_w, qkvT, 256, 768);
    wpack_kernel<<<dim3(128, 1, NL_), 256, 0, stream>>>(ffn_w1, W1P, 256, 1024);
    wpack_kernel<<<dim3(128, 1, NL_), 256, 0, stream>>>(ffn_w2, W2P, 1024, 256);
    wcast_kernel<<<dim3(1, 8, 1), dim3(32, 8), 0, stream>>>(th1_w, th1T, 256, 32);

    sgemm_kernel<<<dim3(D_ / 64, (B_ * NT_) / 64), 256, 0, stream>>>(
        gene, w_in, b_in, Xb, B_ * NT_, D_, TOK_);
    cls_kernel<<<B_, 256, 0, stream>>>(coords, w_cls, b_cls, Xb);

    for (int l = 0; l < NL_; ++l) {
        mfma_gemm8<<<RB2 * (768 / 128), 512, 0, stream>>>(
            Xb, qkvT + (size_t)l * 768 * 256, qkv_b + l * 768, SH, 768, 256, 0);
        attn_kernel<<<dim3(H_, B_), 512, 0, stream>>>(SH, AOb);
        ffn_kernel<<<MPAD / 64, 512, 0, stream>>>(
            Xb, AOb, ln1_g + l * D_, ln1_b + l * D_,
            W1P + (size_t)l * 1024 * 256, W2P + (size_t)l * 256 * 1024,
            ffn_b1 + l * 1024, ffn_b2 + l * D_,
            ln2_g + l * D_, ln2_b + l * D_, Xb);
    }

    head1_kernel<<<MPAD / 128, 256, 0, stream>>>(
        Xb, th1T, th1_b, bn_g, bn_b, th2_w, th2_b, SCp);
    head2_kernel<<<dim3(4, B_), 256, 0, stream>>>(SCp, Xb, out);
}